// Round 1
// baseline (375.296 us; speedup 1.0000x reference)
//
#include <hip/hip_runtime.h>

#define IN_F 256
#define OUT_F 64

// ---------------------------------------------------------------------------
// GEMM: hp[N,64] = h[N,256] @ w[256,64]  (f32, vector ALU — no fp32 MFMA on CDNA4)
// One lane per row. Each lane holds 64-col f32 accumulator in VGPRs.
// w[k][c] is wave-uniform (k,c are loop-uniform) -> compiler emits s_load,
// so the inner loop is ~1 v_fmac per MAC with an SGPR operand.
// ---------------------------------------------------------------------------
__global__ __launch_bounds__(256) void gemm_kernel(const float* __restrict__ h,
                                                   const float* __restrict__ w,
                                                   float* __restrict__ hp, int N) {
    int gwave = (blockIdx.x * blockDim.x + threadIdx.x) >> 6;
    int lane  = threadIdx.x & 63;
    int row   = gwave * 64 + lane;
    int rowc  = row < N ? row : N - 1;   // clamp for safe loads; store is guarded

    float acc[OUT_F];
#pragma unroll
    for (int c = 0; c < OUT_F; ++c) acc[c] = 0.f;

    const float* hrow = h + (size_t)rowc * IN_F;

    for (int k0 = 0; k0 < IN_F; k0 += 64) {
        float hreg[64];
#pragma unroll
        for (int i = 0; i < 64; i += 4) {
            float4 v = *(const float4*)(hrow + k0 + i);
            hreg[i] = v.x; hreg[i + 1] = v.y; hreg[i + 2] = v.z; hreg[i + 3] = v.w;
        }
#pragma unroll 4
        for (int kk = 0; kk < 64; ++kk) {
            int k = k0 + kk;
#pragma unroll
            for (int c = 0; c < OUT_F; ++c) {
                acc[c] = fmaf(hreg[kk], w[k * OUT_F + c], acc[c]);
            }
        }
    }

    if (row < N) {
        float* orow = hp + (size_t)row * OUT_F;
#pragma unroll
        for (int c = 0; c < OUT_F; c += 4) {
            *(float4*)(orow + c) = make_float4(acc[c], acc[c + 1], acc[c + 2], acc[c + 3]);
        }
    }
}

// ---------------------------------------------------------------------------
// Edge kernel: one wave per edge, lane = feature (OUT_F == 64 == wave size).
// dot = wave-reduce(hs*hd); atomicAdd(out[dst] , dot*hs*c) per feature.
// ---------------------------------------------------------------------------
__global__ __launch_bounds__(256) void edge_kernel(const float* __restrict__ hp,
                                                   const int* __restrict__ src,
                                                   const int* __restrict__ dst,
                                                   const float* __restrict__ attw,
                                                   float* __restrict__ out,
                                                   int* __restrict__ deg, int E) {
    int e    = (blockIdx.x * blockDim.x + threadIdx.x) >> 6;
    int lane = threadIdx.x & 63;
    if (e >= E) return;

    int s = src[e];
    int d = dst[e];

    float hs = hp[(size_t)s * OUT_F + lane];
    float hd = hp[(size_t)d * OUT_F + lane];
    float p  = hs * hd;

    // full 64-lane butterfly reduce
#pragma unroll
    for (int off = 32; off >= 1; off >>= 1) p += __shfl_xor(p, off, 64);

    // sum(attention_w) — 8 wave-uniform scalar loads (L2-hot)
    float c = 0.f;
#pragma unroll
    for (int i = 0; i < 8; ++i) c += attw[i];

    atomicAdd(&out[(size_t)d * OUT_F + lane], p * hs * c);
    if (lane == 0) atomicAdd(&deg[d], 1);
}

// ---------------------------------------------------------------------------
// Fixup: zero in-degree nodes keep their projected feature hp.
// ---------------------------------------------------------------------------
__global__ __launch_bounds__(256) void fixup_kernel(const float* __restrict__ hp,
                                                    const int* __restrict__ deg,
                                                    float* __restrict__ out, int N) {
    int v    = (blockIdx.x * blockDim.x + threadIdx.x) >> 6;
    int lane = threadIdx.x & 63;
    if (v >= N) return;
    if (deg[v] == 0) out[(size_t)v * OUT_F + lane] = hp[(size_t)v * OUT_F + lane];
}

extern "C" void kernel_launch(void* const* d_in, const int* in_sizes, int n_in,
                              void* d_out, int out_size, void* d_ws, size_t ws_size,
                              hipStream_t stream) {
    const float* h    = (const float*)d_in[0];
    const float* w    = (const float*)d_in[1];
    const float* attw = (const float*)d_in[2];
    const int*   src  = (const int*)d_in[3];
    const int*   dst  = (const int*)d_in[4];

    int N = in_sizes[0] / IN_F;
    int E = in_sizes[3];

    float* out = (float*)d_out;
    float* hp  = (float*)d_ws;                                   // N*64 f32 = 12.8 MB
    int*   deg = (int*)((char*)d_ws + (size_t)N * OUT_F * sizeof(float)); // N ints

    // d_out / d_ws are re-poisoned to 0xAA before every launch — zero what we accumulate into.
    hipMemsetAsync(d_out, 0, (size_t)N * OUT_F * sizeof(float), stream);
    hipMemsetAsync(deg, 0, (size_t)N * sizeof(int), stream);

    int gemm_waves  = (N + 63) / 64;
    int gemm_blocks = (gemm_waves + 3) / 4;
    gemm_kernel<<<gemm_blocks, 256, 0, stream>>>(h, w, hp, N);

    int edge_blocks = (E + 3) / 4;   // 4 waves/block, 1 edge/wave
    edge_kernel<<<edge_blocks, 256, 0, stream>>>(hp, src, dst, attw, out, deg, E);

    int fix_blocks = (N + 3) / 4;
    fixup_kernel<<<fix_blocks, 256, 0, stream>>>(hp, deg, out, N);
}

// Round 2
// 298.442 us; speedup vs baseline: 1.2575x; 1.2575x over previous
//
#include <hip/hip_runtime.h>

#define IN_F 256
#define OUT_F 64
#define BM 128
#define BK 64
#define LDK 68   // As leading dim (k) padded: 64+4
#define LDC 68   // Bs leading dim (c) padded: 64+4
#define SCAN_B 1024

// ---------------------------------------------------------------------------
// GEMM: hp[N,64] = h[N,256] @ w[256,64]  (f32 vector ALU — no fp32 MFMA).
// 128x64 tile, BK=64 chunks in LDS, 256 threads, 8x4 register outer product.
// A kept row-major in LDS (read along k as float4) -> no transpose conflicts.
// ---------------------------------------------------------------------------
#define FMA4(ACC, S, B) \
    ACC.x = fmaf(S, B.x, ACC.x); ACC.y = fmaf(S, B.y, ACC.y); \
    ACC.z = fmaf(S, B.z, ACC.z); ACC.w = fmaf(S, B.w, ACC.w)

__global__ __launch_bounds__(256) void gemm_kernel(const float* __restrict__ h,
                                                   const float* __restrict__ w,
                                                   float* __restrict__ hp, int N) {
    __shared__ float As[BM][LDK];
    __shared__ float Bs[BK][LDC];

    int tid = threadIdx.x;
    int tn  = tid & 15;   // col group: cols tn*4 .. tn*4+3
    int tm  = tid >> 4;   // row group: rows tm*8 .. tm*8+7
    int row0 = blockIdx.x * BM;

    float4 acc[8];
#pragma unroll
    for (int i = 0; i < 8; ++i) acc[i] = make_float4(0.f, 0.f, 0.f, 0.f);

    for (int k0 = 0; k0 < IN_F; k0 += BK) {
        // stage A: 128 rows x 64 k = 2048 float4, 8 per thread, coalesced
#pragma unroll
        for (int it = 0; it < 8; ++it) {
            int f  = tid + it * 256;
            int r  = f >> 4;          // 16 float4 per row
            int kq = f & 15;
            int gr = row0 + r; if (gr >= N) gr = N - 1;
            float4 v = *(const float4*)(h + (size_t)gr * IN_F + k0 + kq * 4);
            *(float4*)(&As[r][kq * 4]) = v;
        }
        // stage B: 64 k x 64 c = 1024 float4, 4 per thread, coalesced
#pragma unroll
        for (int it = 0; it < 4; ++it) {
            int f  = tid + it * 256;
            int kr = f >> 4;
            int cq = f & 15;
            float4 v = *(const float4*)(w + (size_t)(k0 + kr) * OUT_F + cq * 4);
            *(float4*)(&Bs[kr][cq * 4]) = v;
        }
        __syncthreads();

        for (int kk = 0; kk < BK; kk += 4) {
            float4 b0 = *(float4*)(&Bs[kk + 0][tn * 4]);
            float4 b1 = *(float4*)(&Bs[kk + 1][tn * 4]);
            float4 b2 = *(float4*)(&Bs[kk + 2][tn * 4]);
            float4 b3 = *(float4*)(&Bs[kk + 3][tn * 4]);
#pragma unroll
            for (int i = 0; i < 8; ++i) {
                float4 a = *(float4*)(&As[tm * 8 + i][kk]);
                FMA4(acc[i], a.x, b0);
                FMA4(acc[i], a.y, b1);
                FMA4(acc[i], a.z, b2);
                FMA4(acc[i], a.w, b3);
            }
        }
        __syncthreads();
    }

#pragma unroll
    for (int i = 0; i < 8; ++i) {
        int gr = row0 + tm * 8 + i;
        if (gr < N) *(float4*)(hp + (size_t)gr * OUT_F + tn * 4) = acc[i];
    }
}

// ---------------------------------------------------------------------------
// CSR build: histogram -> block scan -> partial scan -> add offsets -> scatter
// ---------------------------------------------------------------------------
__global__ __launch_bounds__(256) void hist_kernel(const int* __restrict__ dst,
                                                   int* __restrict__ deg, int E) {
    int e = blockIdx.x * blockDim.x + threadIdx.x;
    if (e < E) atomicAdd(&deg[dst[e]], 1);
}

__global__ __launch_bounds__(1024) void scan_blocks(const int* __restrict__ deg,
                                                    int* __restrict__ row_ptr,
                                                    int* __restrict__ partial, int N) {
    __shared__ int sm[SCAN_B];
    int t = threadIdx.x;
    int i = blockIdx.x * SCAN_B + t;
    int v = (i < N) ? deg[i] : 0;
    sm[t] = v;
    __syncthreads();
    for (int off = 1; off < SCAN_B; off <<= 1) {
        int x = 0;
        if (t >= off) x = sm[t - off];
        __syncthreads();
        if (t >= off) sm[t] += x;
        __syncthreads();
    }
    if (i < N) row_ptr[i] = sm[t] - v;          // exclusive within block
    if (t == SCAN_B - 1) partial[blockIdx.x] = sm[t];
}

__global__ void scan_partials(int* __restrict__ partial, int nb) {
    int l = threadIdx.x;
    int v = (l < nb) ? partial[l] : 0;
    int orig = v;
#pragma unroll
    for (int off = 1; off < 64; off <<= 1) {
        int x = __shfl_up(v, off, 64);
        if (l >= off) v += x;
    }
    if (l < nb) partial[l] = v - orig;          // exclusive
}

__global__ __launch_bounds__(256) void scan_add(int* __restrict__ row_ptr,
                                                int* __restrict__ cursor,
                                                const int* __restrict__ partial,
                                                int N, int E) {
    int i = blockIdx.x * blockDim.x + threadIdx.x;
    if (i < N) {
        int v = row_ptr[i] + partial[i >> 10];
        row_ptr[i] = v;
        cursor[i]  = v;
    }
    if (i == 0) row_ptr[N] = E;
}

__global__ __launch_bounds__(256) void scatter_kernel(const int* __restrict__ src,
                                                      const int* __restrict__ dst,
                                                      int* __restrict__ cursor,
                                                      int* __restrict__ srcs, int E) {
    int e = blockIdx.x * blockDim.x + threadIdx.x;
    if (e < E) {
        int d   = dst[e];
        int pos = atomicAdd(&cursor[d], 1);
        srcs[pos] = src[e];
    }
}

// ---------------------------------------------------------------------------
// Accumulate: one wave per dst node, lane = feature. Gather hp[src] rows,
// shfl-reduce dot, register accumulate, one coalesced store. Fuses the
// deg==0 fallback and the *sum(attention_w) scale.
// ---------------------------------------------------------------------------
__global__ __launch_bounds__(256) void accum_kernel(const float* __restrict__ hp,
                                                    const int* __restrict__ row_ptr,
                                                    const int* __restrict__ srcs,
                                                    const float* __restrict__ attw,
                                                    float* __restrict__ out, int N) {
    int v    = (blockIdx.x * blockDim.x + threadIdx.x) >> 6;
    int lane = threadIdx.x & 63;
    if (v >= N) return;

    int beg = row_ptr[v];
    int end = row_ptr[v + 1];
    float hd = hp[(size_t)v * OUT_F + lane];

    float c = 0.f;
#pragma unroll
    for (int i = 0; i < 8; ++i) c += attw[i];

    float acc = 0.f;
    int j = beg;
    float hs = 0.f;
    if (j < end) {
        int s = srcs[j];
        hs = hp[(size_t)s * OUT_F + lane];
    }
    while (j < end) {
        int jn = j + 1;
        float hs_n = 0.f;
        if (jn < end) {                       // prefetch next edge's row
            int sn = srcs[jn];
            hs_n = hp[(size_t)sn * OUT_F + lane];
        }
        float p = hs * hd;
#pragma unroll
        for (int off = 32; off >= 1; off >>= 1) p += __shfl_xor(p, off, 64);
        acc = fmaf(p, hs, acc);               // += dot * hs
        hs = hs_n;
        j = jn;
    }

    out[(size_t)v * OUT_F + lane] = (end > beg) ? acc * c : hd;
}

extern "C" void kernel_launch(void* const* d_in, const int* in_sizes, int n_in,
                              void* d_out, int out_size, void* d_ws, size_t ws_size,
                              hipStream_t stream) {
    const float* h    = (const float*)d_in[0];
    const float* w    = (const float*)d_in[1];
    const float* attw = (const float*)d_in[2];
    const int*   src  = (const int*)d_in[3];
    const int*   dst  = (const int*)d_in[4];

    int N = in_sizes[0] / IN_F;
    int E = in_sizes[3];

    float* out = (float*)d_out;

    // workspace layout (16B aligned chunks)
    char* p = (char*)d_ws;
    float* hp      = (float*)p;            p += (size_t)N * OUT_F * sizeof(float);
    int*   deg     = (int*)p;              p += ((size_t)N + 4) * sizeof(int);
    int*   row_ptr = (int*)p;              p += ((size_t)N + 4) * sizeof(int);
    int*   cursor  = (int*)p;              p += ((size_t)N + 4) * sizeof(int);
    int*   partial = (int*)p;              p += 64 * sizeof(int);
    int*   srcs    = (int*)p;

    hipMemsetAsync(deg, 0, (size_t)N * sizeof(int), stream);

    gemm_kernel<<<(N + BM - 1) / BM, 256, 0, stream>>>(h, w, hp, N);

    hist_kernel<<<(E + 255) / 256, 256, 0, stream>>>(dst, deg, E);

    int nsb = (N + SCAN_B - 1) / SCAN_B;   // 49 for N=50000 (must be <= 64)
    scan_blocks<<<nsb, SCAN_B, 0, stream>>>(deg, row_ptr, partial, N);
    scan_partials<<<1, 64, 0, stream>>>(partial, nsb);
    scan_add<<<(N + 255) / 256, 256, 0, stream>>>(row_ptr, cursor, partial, N, E);

    scatter_kernel<<<(E + 255) / 256, 256, 0, stream>>>(src, dst, cursor, srcs, E);

    accum_kernel<<<(N * 64 + 255) / 256, 256, 0, stream>>>(hp, row_ptr, srcs, attw, out, N);
}

// Round 3
// 239.150 us; speedup vs baseline: 1.5693x; 1.2479x over previous
//
#include <hip/hip_runtime.h>

#define IN_F 256
#define OUT_F 64
#define BM 128
#define BK 64
#define LDK 68
#define LDC 68
#define SCAN_B 1024

#define AS_I(f) __builtin_bit_cast(int, f)
#define AS_F(i) __builtin_bit_cast(float, i)
// v += dpp_moved(v); masked/invalid lanes contribute 0 (old=0, bound_ctrl=1)
#define DPP_ADD(v, ctrl, rmask) \
    v += AS_F(__builtin_amdgcn_update_dpp(0, AS_I(v), ctrl, rmask, 0xf, true))

// Full 64-lane sum of p, result broadcast to all lanes via readlane(63).
// Entirely VALU-pipe (DPP), no LDS swizzles: row_shr 1/2/4/8, row_bcast 15/31.
__device__ __forceinline__ float wave_sum_bcast(float p) {
    DPP_ADD(p, 0x111, 0xf);  // row_shr:1
    DPP_ADD(p, 0x112, 0xf);  // row_shr:2
    DPP_ADD(p, 0x114, 0xf);  // row_shr:4
    DPP_ADD(p, 0x118, 0xf);  // row_shr:8   -> lane15 of each row16 = row sum
    DPP_ADD(p, 0x142, 0xa);  // row_bcast:15 (write rows 1,3) -> lane31, lane63 = half sums
    DPP_ADD(p, 0x143, 0xc);  // row_bcast:31 (write rows 2,3) -> lane63 = total
    return AS_F(__builtin_amdgcn_readlane(AS_I(p), 63));
}

#define FMA4(ACC, S, B) \
    ACC.x = fmaf(S, B.x, ACC.x); ACC.y = fmaf(S, B.y, ACC.y); \
    ACC.z = fmaf(S, B.z, ACC.z); ACC.w = fmaf(S, B.w, ACC.w)

// ---------------------------------------------------------------------------
// GEMM (hp = h @ w, f32 vector ALU) fused with dst-degree histogram.
// Hist waves are latency-bound, GEMM waves VALU-bound -> they co-schedule.
// ---------------------------------------------------------------------------
__global__ __launch_bounds__(256) void gemm_hist_kernel(const float* __restrict__ h,
                                                        const float* __restrict__ w,
                                                        float* __restrict__ hp, int N,
                                                        const int* __restrict__ dst,
                                                        int* __restrict__ deg, int E) {
    int tid = threadIdx.x;

    // histogram part (grid-stride over edges)
    for (int e = blockIdx.x * 256 + tid; e < E; e += gridDim.x * 256)
        atomicAdd(&deg[dst[e]], 1);

    __shared__ float As[BM][LDK];
    __shared__ float Bs[BK][LDC];

    int tn  = tid & 15;
    int tm  = tid >> 4;
    int row0 = blockIdx.x * BM;

    float4 acc[8];
#pragma unroll
    for (int i = 0; i < 8; ++i) acc[i] = make_float4(0.f, 0.f, 0.f, 0.f);

    for (int k0 = 0; k0 < IN_F; k0 += BK) {
#pragma unroll
        for (int it = 0; it < 8; ++it) {
            int f  = tid + it * 256;
            int r  = f >> 4;
            int kq = f & 15;
            int gr = row0 + r; if (gr >= N) gr = N - 1;
            float4 v = *(const float4*)(h + (size_t)gr * IN_F + k0 + kq * 4);
            *(float4*)(&As[r][kq * 4]) = v;
        }
#pragma unroll
        for (int it = 0; it < 4; ++it) {
            int f  = tid + it * 256;
            int kr = f >> 4;
            int cq = f & 15;
            float4 v = *(const float4*)(w + (size_t)(k0 + kr) * OUT_F + cq * 4);
            *(float4*)(&Bs[kr][cq * 4]) = v;
        }
        __syncthreads();

        for (int kk = 0; kk < BK; kk += 4) {
            float4 b0 = *(float4*)(&Bs[kk + 0][tn * 4]);
            float4 b1 = *(float4*)(&Bs[kk + 1][tn * 4]);
            float4 b2 = *(float4*)(&Bs[kk + 2][tn * 4]);
            float4 b3 = *(float4*)(&Bs[kk + 3][tn * 4]);
#pragma unroll
            for (int i = 0; i < 8; ++i) {
                float4 a = *(float4*)(&As[tm * 8 + i][kk]);
                FMA4(acc[i], a.x, b0);
                FMA4(acc[i], a.y, b1);
                FMA4(acc[i], a.z, b2);
                FMA4(acc[i], a.w, b3);
            }
        }
        __syncthreads();
    }

#pragma unroll
    for (int i = 0; i < 8; ++i) {
        int gr = row0 + tm * 8 + i;
        if (gr < N) *(float4*)(hp + (size_t)gr * OUT_F + tn * 4) = acc[i];
    }
}

// ---------------------------------------------------------------------------
// Block-level exclusive scan of deg -> row_ptr (local), per-block totals.
// Wave-shfl scans: 2 __syncthreads instead of 20.
// ---------------------------------------------------------------------------
__global__ __launch_bounds__(SCAN_B) void scan_blocks(const int* __restrict__ deg,
                                                      int* __restrict__ row_ptr,
                                                      int* __restrict__ partial, int N) {
    __shared__ int wsum[16], woff[16];
    int t    = threadIdx.x;
    int lane = t & 63;
    int wid  = t >> 6;
    int i    = blockIdx.x * SCAN_B + t;
    int v    = (i < N) ? deg[i] : 0;

    int x = v;  // wave inclusive scan
#pragma unroll
    for (int off = 1; off < 64; off <<= 1) {
        int y = __shfl_up(x, off, 64);
        if (lane >= off) x += y;
    }
    if (lane == 63) wsum[wid] = x;
    __syncthreads();
    if (t < 16) {
        int s  = wsum[t];
        int xs = s;
#pragma unroll
        for (int off = 1; off < 16; off <<= 1) {
            int y = __shfl_up(xs, off, 64);
            if (t >= off) xs += y;
        }
        woff[t] = xs - s;  // exclusive wave offsets
    }
    __syncthreads();
    int incl = woff[wid] + x;
    if (i < N) row_ptr[i] = incl - v;   // exclusive within block
    if (t == SCAN_B - 1) partial[blockIdx.x] = incl;
}

// ---------------------------------------------------------------------------
// Add block offsets (each block redundantly scans the <=64 partials in-wave),
// write row_ptr and cursor copy. Fuses the old scan_partials kernel.
// ---------------------------------------------------------------------------
__global__ __launch_bounds__(256) void scan_add(int* __restrict__ row_ptr,
                                                int* __restrict__ cursor,
                                                const int* __restrict__ partial,
                                                int nb, int N, int E) {
    __shared__ int poff[64];
    int t = threadIdx.x;
    if (t < 64) {
        int v = (t < nb) ? partial[t] : 0;
        int x = v;
#pragma unroll
        for (int off = 1; off < 64; off <<= 1) {
            int y = __shfl_up(x, off, 64);
            if (t >= off) x += y;
        }
        poff[t] = x - v;  // exclusive
    }
    __syncthreads();
    int i = blockIdx.x * 256 + t;
    if (i < N) {
        int v = row_ptr[i] + poff[i >> 10];
        row_ptr[i] = v;
        cursor[i]  = v;
    }
    if (i == 0) row_ptr[N] = E;
}

__global__ __launch_bounds__(256) void scatter_kernel(const int* __restrict__ src,
                                                      const int* __restrict__ dst,
                                                      int* __restrict__ cursor,
                                                      int* __restrict__ srcs, int E) {
    int e = blockIdx.x * blockDim.x + threadIdx.x;
    if (e < E) {
        int d   = dst[e];
        int pos = atomicAdd(&cursor[d], 1);
        srcs[pos] = src[e];
    }
}

// ---------------------------------------------------------------------------
// Accumulate: one wave per dst node, lane = feature. 4 edges in flight
// (independent gather + DPP-reduce chains), VALU-pipe reduction.
// ---------------------------------------------------------------------------
__global__ __launch_bounds__(256) void accum_kernel(const float* __restrict__ hp,
                                                    const int* __restrict__ row_ptr,
                                                    const int* __restrict__ srcs,
                                                    const float* __restrict__ attw,
                                                    float* __restrict__ out, int N) {
    int v    = (blockIdx.x * blockDim.x + threadIdx.x) >> 6;
    int lane = threadIdx.x & 63;
    if (v >= N) return;

    int beg = row_ptr[v];
    int end = row_ptr[v + 1];
    float hd = hp[(size_t)v * OUT_F + lane];

    float c = 0.f;
#pragma unroll
    for (int i = 0; i < 8; ++i) c += attw[i];

    float acc = 0.f;
    int j = beg;
    for (; j + 4 <= end; j += 4) {
        int s0 = srcs[j], s1 = srcs[j + 1], s2 = srcs[j + 2], s3 = srcs[j + 3];
        float a0 = hp[(size_t)s0 * OUT_F + lane];
        float a1 = hp[(size_t)s1 * OUT_F + lane];
        float a2 = hp[(size_t)s2 * OUT_F + lane];
        float a3 = hp[(size_t)s3 * OUT_F + lane];
        float d0 = wave_sum_bcast(a0 * hd);
        float d1 = wave_sum_bcast(a1 * hd);
        float d2 = wave_sum_bcast(a2 * hd);
        float d3 = wave_sum_bcast(a3 * hd);
        acc = fmaf(d0, a0, acc);
        acc = fmaf(d1, a1, acc);
        acc = fmaf(d2, a2, acc);
        acc = fmaf(d3, a3, acc);
    }
    for (; j < end; ++j) {
        int s = srcs[j];
        float a = hp[(size_t)s * OUT_F + lane];
        float d = wave_sum_bcast(a * hd);
        acc = fmaf(d, a, acc);
    }

    out[(size_t)v * OUT_F + lane] = (end > beg) ? acc * c : hd;
}

extern "C" void kernel_launch(void* const* d_in, const int* in_sizes, int n_in,
                              void* d_out, int out_size, void* d_ws, size_t ws_size,
                              hipStream_t stream) {
    const float* h    = (const float*)d_in[0];
    const float* w    = (const float*)d_in[1];
    const float* attw = (const float*)d_in[2];
    const int*   src  = (const int*)d_in[3];
    const int*   dst  = (const int*)d_in[4];

    int N = in_sizes[0] / IN_F;
    int E = in_sizes[3];

    float* out = (float*)d_out;

    char* p = (char*)d_ws;
    float* hp      = (float*)p;            p += (size_t)N * OUT_F * sizeof(float);
    int*   deg     = (int*)p;              p += ((size_t)N + 4) * sizeof(int);
    int*   row_ptr = (int*)p;              p += ((size_t)N + 4) * sizeof(int);
    int*   cursor  = (int*)p;              p += ((size_t)N + 4) * sizeof(int);
    int*   partial = (int*)p;              p += 64 * sizeof(int);
    int*   srcs    = (int*)p;

    hipMemsetAsync(deg, 0, (size_t)N * sizeof(int), stream);

    int gemm_blocks = (N + BM - 1) / BM;
    gemm_hist_kernel<<<gemm_blocks, 256, 0, stream>>>(h, w, hp, N, dst, deg, E);

    int nsb = (N + SCAN_B - 1) / SCAN_B;   // 49 for N=50000 (must be <= 64)
    scan_blocks<<<nsb, SCAN_B, 0, stream>>>(deg, row_ptr, partial, N);
    scan_add<<<(N + 255) / 256, 256, 0, stream>>>(row_ptr, cursor, partial, nsb, N, E);

    scatter_kernel<<<(E + 255) / 256, 256, 0, stream>>>(src, dst, cursor, srcs, E);

    accum_kernel<<<((size_t)N * 64 + 255) / 256, 256, 0, stream>>>(hp, row_ptr, srcs, attw, out, N);
}